// Round 16
// baseline (360.042 us; speedup 1.0000x reference)
//
#include <hip/hip_runtime.h>
#include <hip/hip_bf16.h>
#include <math.h>

#define BB 4
#define SS 2048
#define EMB 1024
#define HH 8
#define DD 128

typedef __attribute__((ext_vector_type(8))) short bf16x8;
typedef __attribute__((ext_vector_type(4))) float f32x4;
typedef __attribute__((ext_vector_type(2))) unsigned int u32x2;

__device__ __forceinline__ unsigned short f2bf(float f) {
    unsigned u = __builtin_bit_cast(unsigned, f);
    u += 0x7FFFu + ((u >> 16) & 1u);          // RNE
    return (unsigned short)(u >> 16);
}

__device__ __forceinline__ void gload_lds16(const void* g, void* l) {
    __builtin_amdgcn_global_load_lds(
        (const __attribute__((address_space(1))) unsigned int*)g,
        (__attribute__((address_space(3))) unsigned int*)l, 16, 0, 0);
}

#define SB0 __builtin_amdgcn_sched_barrier(0)

// ---------------- fp32 -> bf16 converts (fused, z-indexed) ----------------
__global__ void f2bf3_kernel(const float* __restrict__ a, const float* __restrict__ b,
                             const float* __restrict__ c, unsigned short* __restrict__ dst,
                             int n4) {
    const float* src = blockIdx.z == 0 ? a : (blockIdx.z == 1 ? b : c);
    unsigned short* d = dst + (size_t)blockIdx.z * ((size_t)n4 * 4);
    int i = blockIdx.x * blockDim.x + threadIdx.x;
    int stride = gridDim.x * blockDim.x;
    for (; i < n4; i += stride) {
        float4 f = ((const float4*)src)[i];
        ushort4 o;
        o.x = f2bf(f.x); o.y = f2bf(f.y); o.z = f2bf(f.z); o.w = f2bf(f.w);
        ((ushort4*)d)[i] = o;
    }
}

__global__ void f2bf4_kernel(const float* __restrict__ a, const float* __restrict__ b,
                             const float* __restrict__ c, const float* __restrict__ e,
                             unsigned short* __restrict__ dst, int n4) {
    const float* src = blockIdx.z == 0 ? a : (blockIdx.z == 1 ? b : (blockIdx.z == 2 ? c : e));
    unsigned short* d = dst + (size_t)blockIdx.z * ((size_t)n4 * 4);
    int i = blockIdx.x * blockDim.x + threadIdx.x;
    int stride = gridDim.x * blockDim.x;
    for (; i < n4; i += stride) {
        float4 f = ((const float4*)src)[i];
        ushort4 o;
        o.x = f2bf(f.x); o.y = f2bf(f.y); o.z = f2bf(f.z); o.w = f2bf(f.w);
        ((ushort4*)d)[i] = o;
    }
}

// ---------------- GEMM core: C = A @ Bw^T + bias (2-phase dbuf) ----------------
// MODE 0: out bf16 scattered to [B,H,S,D], scaled. MODE 1: out fp32 [M,1024].
template <int MODE>
__device__ __forceinline__ void gemm_core(const unsigned short* __restrict__ A,
                                          const unsigned short* __restrict__ Bw,
                                          const float* __restrict__ bias,
                                          void* __restrict__ Cout, float scale)
{
    __shared__ short As[2][128 * 32];
    __shared__ short Bs[2][128 * 32];
    const int K = 1024;
    const int m0 = blockIdx.x * 128, n0 = blockIdx.y * 128;
    const int t = threadIdx.x;
    const int lane = t & 63, w = t >> 6;
    const int wr = w >> 1, wc = w & 1;
    const int g = lane >> 4, li = lane & 15;
    f32x4 acc[4][4] = {};

    auto stage = [&](int k0, int buf) {
        #pragma unroll
        for (int i = 0; i < 2; ++i) {
            int idx = i * 256 + t;
            int row = idx >> 2, col = (idx & 3) * 8;
            gload_lds16(A  + (size_t)(m0 + row) * K + k0 + col, &As[buf][idx * 8]);
            gload_lds16(Bw + (size_t)(n0 + row) * K + k0 + col, &Bs[buf][idx * 8]);
        }
    };

    stage(0, 0);
    for (int ki = 0; ki < 32; ++ki) {
        const int cur = ki & 1;
        if (ki < 31) {
            stage((ki + 1) * 32, cur ^ 1);
            asm volatile("s_waitcnt vmcnt(4)" ::: "memory");
        } else {
            asm volatile("s_waitcnt vmcnt(0)" ::: "memory");
        }
        SB0; __builtin_amdgcn_s_barrier(); SB0;

        bf16x8 af[4], bfr[4];
        #pragma unroll
        for (int mi = 0; mi < 4; ++mi)
            af[mi] = *(const bf16x8*)&As[cur][(wr * 64 + mi * 16 + li) * 32 + g * 8];
        #pragma unroll
        for (int ni = 0; ni < 4; ++ni)
            bfr[ni] = *(const bf16x8*)&Bs[cur][(wc * 64 + ni * 16 + li) * 32 + g * 8];
        #pragma unroll
        for (int mi = 0; mi < 4; ++mi) {
            #pragma unroll
            for (int ni = 0; ni < 4; ++ni)
                acc[mi][ni] = __builtin_amdgcn_mfma_f32_16x16x32_bf16(
                    af[mi], bfr[ni], acc[mi][ni], 0, 0, 0);
        }
        asm volatile("s_waitcnt lgkmcnt(0)" ::: "memory");
        SB0; __builtin_amdgcn_s_barrier(); SB0;
    }

    #pragma unroll
    for (int mi = 0; mi < 4; ++mi) {
        #pragma unroll
        for (int ni = 0; ni < 4; ++ni) {
            int n = n0 + wc * 64 + ni * 16 + li;
            float bv = bias[n];
            #pragma unroll
            for (int i = 0; i < 4; ++i) {
                int m = m0 + wr * 64 + mi * 16 + g * 4 + i;
                float v = acc[mi][ni][i] + bv;
                if (MODE == 0) {
                    v *= scale;
                    int b = m >> 11, s = m & 2047, h = n >> 7, d = n & 127;
                    ((unsigned short*)Cout)[((((size_t)b * HH + h) * SS + s) << 7) + d] = f2bf(v);
                } else {
                    ((float*)Cout)[(size_t)m * EMB + n] = v;
                }
            }
        }
    }
}

// Fused QKV projection: gridDim.z = 3 selects (Wq->Qb), (Wk->Kb), (Wv->Vb)
__global__ __launch_bounds__(256, 2)
void gemm_qkv(const unsigned short* __restrict__ XB, const unsigned short* __restrict__ WB,
              const float* __restrict__ bq, const float* __restrict__ bk,
              const float* __restrict__ bv, unsigned short* __restrict__ QKVb, float qscale)
{
    const size_t NX = (size_t)BB * SS * EMB;
    const size_t NW = (size_t)EMB * EMB;
    const int z = blockIdx.z;
    const float* bias = z == 0 ? bq : (z == 1 ? bk : bv);
    gemm_core<0>(XB + z * NX, WB + z * NW, bias, QKVb + z * NX, z == 0 ? qscale : 1.f);
}

__global__ __launch_bounds__(256, 2)
void gemm_out(const unsigned short* __restrict__ Ob, const unsigned short* __restrict__ Wo,
              const float* __restrict__ bo, float* __restrict__ outx)
{
    gemm_core<1>(Ob, Wo, bo, outx, 1.f);
}

// ---------------- fused attention (R12/R15 + counted pass-B waits) ----------------
// grid (32 q-tiles, 32 bh), 4 waves x 64, 16 q-rows/wave, LDS 42.5KB -> 3 blocks/CU.
// SWAPPED QK (proven): lane li = q-row, f32x4 NT prob stores, cvt_pk Ps, scalar rl.
// NEW vs R15 (pass B only): both __syncthreads -> raw barriers with COUNTED waits.
//   sync#1: raw s_barrier only (no vmcnt drain: NT stores + V(kt+1) loads stay
//           in flight; R15 drained their full DRAM-ack/HBM latency here).
//   sync#2: lgkmcnt(0) (scatter writes visible) + vmcnt(4): in-order retirement
//           completes the oldest 20 in-flight ops (16 stores + 4 K-gloads)
//           while the 4 youngest (V(kt+1) loads) linger across the barrier.
__global__ __launch_bounds__(256, 2)
void attn_kernel(const unsigned short* __restrict__ Qb,   // [B,H,S,D] bf16, pre-scaled by log2e/sqrt(D)
                 const unsigned short* __restrict__ Kb,
                 const unsigned short* __restrict__ Vb,
                 float* __restrict__ attn,                 // [B,H,S,S] fp32
                 unsigned short* __restrict__ Ob)          // [B*S, EMB] bf16
{
    __shared__ short Ks[64 * 128];     // K tile (XOR-swizzled rows) / pass-A buf0
    __shared__ short Vt[128 * 64];     // pass B: V^T (swizzled); pass A: K buf1
    __shared__ short Ps[4][16 * 72];   // per-wave P (bf16), stride 72 (144B rows)

    const int t = threadIdx.x;
    const int lane = t & 63, w = t >> 6;
    const int g = lane >> 4, li = lane & 15;
    const int bh = blockIdx.y;
    const int q0 = blockIdx.x * 64 + w * 16;

    const unsigned short* Kbh = Kb + (size_t)bh * SS * DD;
    const unsigned short* Vbh = Vb + (size_t)bh * SS * DD;

    bf16x8 qf[4];
    {
        const unsigned short* qp = Qb + ((size_t)bh * SS + q0 + li) * DD + g * 8;
        #pragma unroll
        for (int kk = 0; kk < 4; ++kk) qf[kk] = *(const bf16x8*)(qp + kk * 32);
    }

    float lacc = 0.f;

    auto stageK = [&](int kt2, char* dst) {
        const char* ksrc = (const char*)(Kbh + kt2 * 64 * DD);
        #pragma unroll
        for (int i = 0; i < 4; ++i) {
            int lb = (i * 256 + t) * 16;
            int row = lb >> 8;
            gload_lds16(ksrc + (lb ^ ((row & 7) << 4)), dst + lb);
        }
    };

    // ---- pass A: K double-buffered with counted vmcnt, raw barriers (proven) ----
    stageK(0, (char*)Ks);
    for (int kt = 0; kt < 32; ++kt) {
        const char* cur = (kt & 1) ? (const char*)Vt : (const char*)Ks;
        char* nxt = (kt & 1) ? (char*)Ks : (char*)Vt;
        if (kt < 31) {
            stageK(kt + 1, nxt);
            asm volatile("s_waitcnt vmcnt(4)" ::: "memory");
        } else {
            asm volatile("s_waitcnt vmcnt(0)" ::: "memory");
        }
        SB0; __builtin_amdgcn_s_barrier(); SB0;

        #pragma unroll
        for (int kc = 0; kc < 4; ++kc) {
            f32x4 a = {0.f, 0.f, 0.f, 0.f};
            int row = kc * 16 + li;
            int sw = (row & 7) << 4;
            #pragma unroll
            for (int kk = 0; kk < 4; ++kk) {
                bf16x8 kf = *(const bf16x8*)(cur + row * 256 + ((kk * 64 + g * 16) ^ sw));
                a = __builtin_amdgcn_mfma_f32_16x16x32_bf16(kf, qf[kk], a, 0, 0, 0);  // SWAPPED
            }
            lacc += __builtin_amdgcn_exp2f(a[0]) + __builtin_amdgcn_exp2f(a[1])
                  + __builtin_amdgcn_exp2f(a[2]) + __builtin_amdgcn_exp2f(a[3]);
        }
        __builtin_amdgcn_s_barrier(); SB0;
    }

    // reduce over g-groups (lane bits 4,5): all of q=li's partials
    float ts = lacc;
    ts += __shfl_xor(ts, 16, 64);
    ts += __shfl_xor(ts, 32, 64);
    const float rl = 1.f / ts;

    // ---- pass B (counted waits; data flow identical to R15) ----
    f32x4 O[8] = {};
    float* arow = attn + (size_t)bh * SS * SS;

    // prologue: V reg-loads for tile 0
    bf16x8 va[2], vbr[2];
    #pragma unroll
    for (int i = 0; i < 2; ++i) {
        int idx = i * 256 + t;
        int k0 = (idx >> 4) * 2, d0 = (idx & 15) * 8;
        va[i]  = *(const bf16x8*)(Vbh + k0 * DD + d0);
        vbr[i] = *(const bf16x8*)(Vbh + (k0 + 1) * DD + d0);
    }

    for (int kt = 0; kt < 32; ++kt) {
        // sync#1: RAW barrier — all waves' Ks/Vt(kt-1) LDS reads are complete
        // (consumed via per-use dependency waits). No VMEM drain.
        SB0; __builtin_amdgcn_s_barrier(); SB0;
        // stage K(kt) (async DMA to LDS)
        const char* ksrc = (const char*)(Kbh + kt * 64 * DD);
        #pragma unroll
        for (int i = 0; i < 4; ++i) {
            int lb = (i * 256 + t) * 16;
            int row = lb >> 8;
            gload_lds16(ksrc + (lb ^ ((row & 7) << 4)), (char*)Ks + lb);
        }
        // scatter V^T(kt) from regs (compiler inserts the precise counted
        // vmcnt for va/vbr): paired k-rows -> 4B writes, conflict-free
        #pragma unroll
        for (int i = 0; i < 2; ++i) {
            int idx = i * 256 + t;
            int kpair = idx >> 4, d0 = (idx & 15) * 8;
            #pragma unroll
            for (int j = 0; j < 8; ++j) {
                unsigned pk = (unsigned)(unsigned short)va[i][j]
                            | ((unsigned)(unsigned short)vbr[i][j] << 16);
                int d = d0 + j;
                int ba = (d * 128 + kpair * 4) ^ (((d >> 3) & 7) << 4);
                *(unsigned*)((char*)Vt + ba) = pk;
            }
        }
        // T14: issue V(kt+1) reg-loads BEFORE sync#2 so the counted wait can
        // leave them in flight (their latency hides under QK^T+PV of kt)
        if (kt < 31) {
            const unsigned short* vn = Vbh + (kt + 1) * 64 * DD;
            #pragma unroll
            for (int i = 0; i < 2; ++i) {
                int idx = i * 256 + t;
                int k0 = (idx >> 4) * 2, d0 = (idx & 15) * 8;
                va[i]  = *(const bf16x8*)(vn + k0 * DD + d0);
                vbr[i] = *(const bf16x8*)(vn + (k0 + 1) * DD + d0);
            }
            SB0;
            // sync#2 counted: oldest 20 in-flight (16 NT stores of kt-1 +
            // 4 K-gloads) retire; 4 V(kt+1) loads stay outstanding.
            asm volatile("s_waitcnt lgkmcnt(0)" ::: "memory");
            asm volatile("s_waitcnt vmcnt(4)" ::: "memory");
        } else {
            SB0;
            asm volatile("s_waitcnt lgkmcnt(0)" ::: "memory");
            asm volatile("s_waitcnt vmcnt(0)" ::: "memory");  // no younger ops: full drain
        }
        SB0; __builtin_amdgcn_s_barrier(); SB0;

        // QK^T swapped: lane li = q-row, values = 4 consecutive k
        #pragma unroll
        for (int kc = 0; kc < 4; ++kc) {
            f32x4 a = {0.f, 0.f, 0.f, 0.f};
            int row = kc * 16 + li;
            int sw = (row & 7) << 4;
            #pragma unroll
            for (int kk = 0; kk < 4; ++kk) {
                bf16x8 kf = *(const bf16x8*)((const char*)Ks + row * 256 + ((kk * 64 + g * 16) ^ sw));
                a = __builtin_amdgcn_mfma_f32_16x16x32_bf16(kf, qf[kk], a, 0, 0, 0);  // SWAPPED
            }
            float p0 = __builtin_amdgcn_exp2f(a[0]) * rl;
            float p1 = __builtin_amdgcn_exp2f(a[1]) * rl;
            float p2 = __builtin_amdgcn_exp2f(a[2]) * rl;
            float p3 = __builtin_amdgcn_exp2f(a[3]) * rl;
            // one float4 nontemporal store: P[q=q0+li][k = kt*64 + kc*16 + g*4 .. +3]
            f32x4 pv = {p0, p1, p2, p3};
            __builtin_nontemporal_store(pv,
                (f32x4*)(arow + (size_t)(q0 + li) * SS + kt * 64 + kc * 16 + g * 4));
            // one b64 Ps write: 4 bf16 via 2 cvt_pk
            unsigned pk0, pk1;
            asm("v_cvt_pk_bf16_f32 %0, %1, %2" : "=v"(pk0) : "v"(p0), "v"(p1));
            asm("v_cvt_pk_bf16_f32 %0, %1, %2" : "=v"(pk1) : "v"(p2), "v"(p3));
            u32x2 pw = {pk0, pk1};
            *(u32x2*)((char*)&Ps[w][0] + li * 144 + kc * 32 + g * 8) = pw;
        }
        // this wave's Ps writes visible to its own reads (LDS only, fast)
        asm volatile("s_waitcnt lgkmcnt(0)" ::: "memory");
        SB0;

        bf16x8 pf0 = *(const bf16x8*)((const char*)&Ps[w][0] + li * 144 + g * 16);
        bf16x8 pf1 = *(const bf16x8*)((const char*)&Ps[w][0] + li * 144 + 64 + g * 16);
        #pragma unroll
        for (int dt = 0; dt < 8; ++dt) {
            int dr = dt * 16 + li;
            int vsw = ((dr >> 3) & 7) << 4;
            bf16x8 vf0 = *(const bf16x8*)((const char*)Vt + dr * 128 + ((g * 16) ^ vsw));
            bf16x8 vf1 = *(const bf16x8*)((const char*)Vt + dr * 128 + ((64 + g * 16) ^ vsw));
            O[dt] = __builtin_amdgcn_mfma_f32_16x16x32_bf16(pf0, vf0, O[dt], 0, 0, 0);
            O[dt] = __builtin_amdgcn_mfma_f32_16x16x32_bf16(pf1, vf1, O[dt], 0, 0, 0);
        }
    }

    const int b = bh >> 3, h = bh & 7;
    #pragma unroll
    for (int dt = 0; dt < 8; ++dt) {
        #pragma unroll
        for (int i = 0; i < 4; ++i) {
            size_t r = (size_t)b * SS + q0 + g * 4 + i;
            Ob[r * EMB + h * DD + dt * 16 + li] = f2bf(O[dt][i]);
        }
    }
}

extern "C" void kernel_launch(void* const* d_in, const int* in_sizes, int n_in,
                              void* d_out, int out_size, void* d_ws, size_t ws_size,
                              hipStream_t stream)
{
    const float* q  = (const float*)d_in[0];
    const float* k  = (const float*)d_in[1];
    const float* v  = (const float*)d_in[2];
    const float* Wq = (const float*)d_in[3];
    const float* bq = (const float*)d_in[4];
    const float* Wk = (const float*)d_in[5];
    const float* bk = (const float*)d_in[6];
    const float* Wv = (const float*)d_in[7];
    const float* bv = (const float*)d_in[8];
    const float* Wo = (const float*)d_in[9];
    const float* bo = (const float*)d_in[10];

    const size_t NX = (size_t)BB * SS * EMB;   // 8,388,608
    const size_t NW = (size_t)EMB * EMB;       // 1,048,576

    unsigned short* Qb = (unsigned short*)d_ws;      // Qb|Kb|Vb contiguous
    unsigned short* Ob = Qb + 3 * NX;                // [B*S, EMB]
    unsigned short* WB = Ob + NX;                    // 4*NW bf16

    float* outx = (float*)d_out;             // [B,S,EMB]
    float* attn = outx + NX;                 // [B,H,S,S]
    unsigned short* XB = (unsigned short*)attn;  // staged bf16 q/k/v (overwritten later)

    f2bf3_kernel<<<dim3(1024, 1, 3), 256, 0, stream>>>(q, k, v, XB, (int)(NX / 4));
    f2bf4_kernel<<<dim3(128, 1, 4), 256, 0, stream>>>(Wq, Wk, Wv, Wo, WB, (int)(NW / 4));

    const float qscale = 1.4426950408889634f / sqrtf((float)DD); // log2(e)/sqrt(D)
    gemm_qkv<<<dim3(64, 8, 3), 256, 0, stream>>>(XB, WB, bq, bk, bv, Qb, qscale);

    attn_kernel<<<dim3(32, 32), 256, 0, stream>>>(Qb, Qb + NX, Qb + 2 * NX, attn, Ob);

    gemm_out<<<dim3(64, 8), 256, 0, stream>>>(Ob, WB + 3 * NW, bo, outx);
}

// Round 17
// 353.926 us; speedup vs baseline: 1.0173x; 1.0173x over previous
//
#include <hip/hip_runtime.h>
#include <hip/hip_bf16.h>
#include <math.h>

#define BB 4
#define SS 2048
#define EMB 1024
#define HH 8
#define DD 128

typedef __attribute__((ext_vector_type(8))) short bf16x8;
typedef __attribute__((ext_vector_type(4))) float f32x4;
typedef __attribute__((ext_vector_type(2))) unsigned int u32x2;

__device__ __forceinline__ unsigned short f2bf(float f) {
    unsigned u = __builtin_bit_cast(unsigned, f);
    u += 0x7FFFu + ((u >> 16) & 1u);          // RNE
    return (unsigned short)(u >> 16);
}

__device__ __forceinline__ void gload_lds16(const void* g, void* l) {
    __builtin_amdgcn_global_load_lds(
        (const __attribute__((address_space(1))) unsigned int*)g,
        (__attribute__((address_space(3))) unsigned int*)l, 16, 0, 0);
}

#define SB0 __builtin_amdgcn_sched_barrier(0)

// ---------------- fp32 -> bf16 converts (fused, z-indexed) ----------------
__global__ void f2bf3_kernel(const float* __restrict__ a, const float* __restrict__ b,
                             const float* __restrict__ c, unsigned short* __restrict__ dst,
                             int n4) {
    const float* src = blockIdx.z == 0 ? a : (blockIdx.z == 1 ? b : c);
    unsigned short* d = dst + (size_t)blockIdx.z * ((size_t)n4 * 4);
    int i = blockIdx.x * blockDim.x + threadIdx.x;
    int stride = gridDim.x * blockDim.x;
    for (; i < n4; i += stride) {
        float4 f = ((const float4*)src)[i];
        ushort4 o;
        o.x = f2bf(f.x); o.y = f2bf(f.y); o.z = f2bf(f.z); o.w = f2bf(f.w);
        ((ushort4*)d)[i] = o;
    }
}

__global__ void f2bf4_kernel(const float* __restrict__ a, const float* __restrict__ b,
                             const float* __restrict__ c, const float* __restrict__ e,
                             unsigned short* __restrict__ dst, int n4) {
    const float* src = blockIdx.z == 0 ? a : (blockIdx.z == 1 ? b : (blockIdx.z == 2 ? c : e));
    unsigned short* d = dst + (size_t)blockIdx.z * ((size_t)n4 * 4);
    int i = blockIdx.x * blockDim.x + threadIdx.x;
    int stride = gridDim.x * blockDim.x;
    for (; i < n4; i += stride) {
        float4 f = ((const float4*)src)[i];
        ushort4 o;
        o.x = f2bf(f.x); o.y = f2bf(f.y); o.z = f2bf(f.z); o.w = f2bf(f.w);
        ((ushort4*)d)[i] = o;
    }
}

// ---------------- GEMM core: C = A @ Bw^T + bias (2-phase dbuf) ----------------
// MODE 0: out bf16 scattered to [B,H,S,D], scaled. MODE 1: out fp32 [M,1024].
template <int MODE>
__device__ __forceinline__ void gemm_core(const unsigned short* __restrict__ A,
                                          const unsigned short* __restrict__ Bw,
                                          const float* __restrict__ bias,
                                          void* __restrict__ Cout, float scale)
{
    __shared__ short As[2][128 * 32];
    __shared__ short Bs[2][128 * 32];
    const int K = 1024;
    const int m0 = blockIdx.x * 128, n0 = blockIdx.y * 128;
    const int t = threadIdx.x;
    const int lane = t & 63, w = t >> 6;
    const int wr = w >> 1, wc = w & 1;
    const int g = lane >> 4, li = lane & 15;
    f32x4 acc[4][4] = {};

    auto stage = [&](int k0, int buf) {
        #pragma unroll
        for (int i = 0; i < 2; ++i) {
            int idx = i * 256 + t;
            int row = idx >> 2, col = (idx & 3) * 8;
            gload_lds16(A  + (size_t)(m0 + row) * K + k0 + col, &As[buf][idx * 8]);
            gload_lds16(Bw + (size_t)(n0 + row) * K + k0 + col, &Bs[buf][idx * 8]);
        }
    };

    stage(0, 0);
    for (int ki = 0; ki < 32; ++ki) {
        const int cur = ki & 1;
        if (ki < 31) {
            stage((ki + 1) * 32, cur ^ 1);
            asm volatile("s_waitcnt vmcnt(4)" ::: "memory");
        } else {
            asm volatile("s_waitcnt vmcnt(0)" ::: "memory");
        }
        SB0; __builtin_amdgcn_s_barrier(); SB0;

        bf16x8 af[4], bfr[4];
        #pragma unroll
        for (int mi = 0; mi < 4; ++mi)
            af[mi] = *(const bf16x8*)&As[cur][(wr * 64 + mi * 16 + li) * 32 + g * 8];
        #pragma unroll
        for (int ni = 0; ni < 4; ++ni)
            bfr[ni] = *(const bf16x8*)&Bs[cur][(wc * 64 + ni * 16 + li) * 32 + g * 8];
        #pragma unroll
        for (int mi = 0; mi < 4; ++mi) {
            #pragma unroll
            for (int ni = 0; ni < 4; ++ni)
                acc[mi][ni] = __builtin_amdgcn_mfma_f32_16x16x32_bf16(
                    af[mi], bfr[ni], acc[mi][ni], 0, 0, 0);
        }
        asm volatile("s_waitcnt lgkmcnt(0)" ::: "memory");
        SB0; __builtin_amdgcn_s_barrier(); SB0;
    }

    #pragma unroll
    for (int mi = 0; mi < 4; ++mi) {
        #pragma unroll
        for (int ni = 0; ni < 4; ++ni) {
            int n = n0 + wc * 64 + ni * 16 + li;
            float bv = bias[n];
            #pragma unroll
            for (int i = 0; i < 4; ++i) {
                int m = m0 + wr * 64 + mi * 16 + g * 4 + i;
                float v = acc[mi][ni][i] + bv;
                if (MODE == 0) {
                    v *= scale;
                    int b = m >> 11, s = m & 2047, h = n >> 7, d = n & 127;
                    ((unsigned short*)Cout)[((((size_t)b * HH + h) * SS + s) << 7) + d] = f2bf(v);
                } else {
                    ((float*)Cout)[(size_t)m * EMB + n] = v;
                }
            }
        }
    }
}

// Fused QKV projection: gridDim.z = 3 selects (Wq->Qb), (Wk->Kb), (Wv->Vb)
__global__ __launch_bounds__(256, 2)
void gemm_qkv(const unsigned short* __restrict__ XB, const unsigned short* __restrict__ WB,
              const float* __restrict__ bq, const float* __restrict__ bk,
              const float* __restrict__ bv, unsigned short* __restrict__ QKVb, float qscale)
{
    const size_t NX = (size_t)BB * SS * EMB;
    const size_t NW = (size_t)EMB * EMB;
    const int z = blockIdx.z;
    const float* bias = z == 0 ? bq : (z == 1 ? bk : bv);
    gemm_core<0>(XB + z * NX, WB + z * NW, bias, QKVb + z * NX, z == 0 ? qscale : 1.f);
}

__global__ __launch_bounds__(256, 2)
void gemm_out(const unsigned short* __restrict__ Ob, const unsigned short* __restrict__ Wo,
              const float* __restrict__ bo, float* __restrict__ outx)
{
    gemm_core<1>(Ob, Wo, bo, outx, 1.f);
}

// ---------------- fused attention (R5 structure + SWAPPED QK^T) ----------------
// grid (32 q-tiles, 32 bh), 4 waves x 64, 16 q-rows/wave, LDS 42.5KB -> 3 blocks/CU.
// SWAPPED QK: mfma(kf, qf) -- same registers/reads as mfma(qf, kf), but output
// S^T: lane li holds 4 CONSECUTIVE k for ONE q-row (q = q0+li). Gains:
//   - attn prob stores: 16 scalar -> 4 float4 nontemporal (full fp32 precision)
//   - Ps writes: 16 ds_write_b16 + 16 f2bf -> 4 ds_write_b64 + 8 v_cvt_pk_bf16_f32
//   - rl: one scalar per lane (pass-A butterfly 4 steps -> 2)
// PV, V^T scatter, staging, epilogue identical to R5 (proven).
__global__ __launch_bounds__(256, 2)
void attn_kernel(const unsigned short* __restrict__ Qb,   // [B,H,S,D] bf16, pre-scaled by log2e/sqrt(D)
                 const unsigned short* __restrict__ Kb,
                 const unsigned short* __restrict__ Vb,
                 float* __restrict__ attn,                 // [B,H,S,S] fp32
                 unsigned short* __restrict__ Ob)          // [B*S, EMB] bf16
{
    __shared__ short Ks[64 * 128];     // K tile (XOR-swizzled rows) / pass-A buf0
    __shared__ short Vt[128 * 64];     // pass B: V^T (swizzled); pass A: K buf1
    __shared__ short Ps[4][16 * 72];   // per-wave P (bf16), stride 72: b64 writes 2-way-free,
                                       // b128 reads bank-balanced, 16B-aligned rows

    const int t = threadIdx.x;
    const int lane = t & 63, w = t >> 6;
    const int g = lane >> 4, li = lane & 15;
    const int bh = blockIdx.y;
    const int q0 = blockIdx.x * 64 + w * 16;

    const unsigned short* Kbh = Kb + (size_t)bh * SS * DD;
    const unsigned short* Vbh = Vb + (size_t)bh * SS * DD;

    bf16x8 qf[4];
    {
        const unsigned short* qp = Qb + ((size_t)bh * SS + q0 + li) * DD + g * 8;
        #pragma unroll
        for (int kk = 0; kk < 4; ++kk) qf[kk] = *(const bf16x8*)(qp + kk * 32);
    }

    float lacc = 0.f;

    auto stageK = [&](int kt2, char* dst) {
        const char* ksrc = (const char*)(Kbh + kt2 * 64 * DD);
        #pragma unroll
        for (int i = 0; i < 4; ++i) {
            int lb = (i * 256 + t) * 16;
            int row = lb >> 8;
            gload_lds16(ksrc + (lb ^ ((row & 7) << 4)), dst + lb);
        }
    };

    // ---- pass A: K double-buffered with counted vmcnt, raw barriers (proven) ----
    stageK(0, (char*)Ks);
    for (int kt = 0; kt < 32; ++kt) {
        const char* cur = (kt & 1) ? (const char*)Vt : (const char*)Ks;
        char* nxt = (kt & 1) ? (char*)Ks : (char*)Vt;
        if (kt < 31) {
            stageK(kt + 1, nxt);
            asm volatile("s_waitcnt vmcnt(4)" ::: "memory");
        } else {
            asm volatile("s_waitcnt vmcnt(0)" ::: "memory");
        }
        SB0; __builtin_amdgcn_s_barrier(); SB0;

        #pragma unroll
        for (int kc = 0; kc < 4; ++kc) {
            f32x4 a = {0.f, 0.f, 0.f, 0.f};
            int row = kc * 16 + li;
            int sw = (row & 7) << 4;
            #pragma unroll
            for (int kk = 0; kk < 4; ++kk) {
                bf16x8 kf = *(const bf16x8*)(cur + row * 256 + ((kk * 64 + g * 16) ^ sw));
                a = __builtin_amdgcn_mfma_f32_16x16x32_bf16(kf, qf[kk], a, 0, 0, 0);  // SWAPPED
            }
            lacc += __builtin_amdgcn_exp2f(a[0]) + __builtin_amdgcn_exp2f(a[1])
                  + __builtin_amdgcn_exp2f(a[2]) + __builtin_amdgcn_exp2f(a[3]);
        }
        __builtin_amdgcn_s_barrier(); SB0;
    }

    // reduce over g-groups (lane bits 4,5): all of q=li's partials
    float ts = lacc;
    ts += __shfl_xor(ts, 16, 64);
    ts += __shfl_xor(ts, 32, 64);
    const float rl = 1.f / ts;

    // ---- pass B (R5 structure: single buffer, 2x syncthreads, T14 V-prefetch) ----
    f32x4 O[8] = {};
    float* arow = attn + (size_t)bh * SS * SS;

    // prologue: V reg-loads for tile 0
    bf16x8 va[2], vbr[2];
    #pragma unroll
    for (int i = 0; i < 2; ++i) {
        int idx = i * 256 + t;
        int k0 = (idx >> 4) * 2, d0 = (idx & 15) * 8;
        va[i]  = *(const bf16x8*)(Vbh + k0 * DD + d0);
        vbr[i] = *(const bf16x8*)(Vbh + (k0 + 1) * DD + d0);
    }

    for (int kt = 0; kt < 32; ++kt) {
        __syncthreads();   // prev iteration's LDS reads done (also drains vmcnt: va/vbr ready)
        // stage K (async to LDS)
        const char* ksrc = (const char*)(Kbh + kt * 64 * DD);
        #pragma unroll
        for (int i = 0; i < 4; ++i) {
            int lb = (i * 256 + t) * 16;
            int row = lb >> 8;
            gload_lds16(ksrc + (lb ^ ((row & 7) << 4)), (char*)Ks + lb);
        }
        // scatter V^T from regs: paired k-rows -> 4B writes, conflict-free
        #pragma unroll
        for (int i = 0; i < 2; ++i) {
            int idx = i * 256 + t;
            int kpair = idx >> 4, d0 = (idx & 15) * 8;
            #pragma unroll
            for (int j = 0; j < 8; ++j) {
                unsigned pk = (unsigned)(unsigned short)va[i][j]
                            | ((unsigned)(unsigned short)vbr[i][j] << 16);
                int d = d0 + j;
                int ba = (d * 128 + kpair * 4) ^ (((d >> 3) & 7) << 4);
                *(unsigned*)((char*)Vt + ba) = pk;
            }
        }
        __syncthreads();   // K gloads (vmcnt) + V^T writes (lgkm) visible

        // T14: issue next tile's V reg-loads now; latency hides under QK^T+PV
        if (kt < 31) {
            const unsigned short* vn = Vbh + (kt + 1) * 64 * DD;
            #pragma unroll
            for (int i = 0; i < 2; ++i) {
                int idx = i * 256 + t;
                int k0 = (idx >> 4) * 2, d0 = (idx & 15) * 8;
                va[i]  = *(const bf16x8*)(vn + k0 * DD + d0);
                vbr[i] = *(const bf16x8*)(vn + (k0 + 1) * DD + d0);
            }
        }

        // QK^T swapped: lane li = q-row, values = 4 consecutive k
        #pragma unroll
        for (int kc = 0; kc < 4; ++kc) {
            f32x4 a = {0.f, 0.f, 0.f, 0.f};
            int row = kc * 16 + li;
            int sw = (row & 7) << 4;
            #pragma unroll
            for (int kk = 0; kk < 4; ++kk) {
                bf16x8 kf = *(const bf16x8*)((const char*)Ks + row * 256 + ((kk * 64 + g * 16) ^ sw));
                a = __builtin_amdgcn_mfma_f32_16x16x32_bf16(kf, qf[kk], a, 0, 0, 0);  // SWAPPED
            }
            float p0 = __builtin_amdgcn_exp2f(a[0]) * rl;
            float p1 = __builtin_amdgcn_exp2f(a[1]) * rl;
            float p2 = __builtin_amdgcn_exp2f(a[2]) * rl;
            float p3 = __builtin_amdgcn_exp2f(a[3]) * rl;
            // one float4 nontemporal store: P[q=q0+li][k = kt*64 + kc*16 + g*4 .. +3]
            f32x4 pv = {p0, p1, p2, p3};
            __builtin_nontemporal_store(pv,
                (f32x4*)(arow + (size_t)(q0 + li) * SS + kt * 64 + kc * 16 + g * 4));
            // one b64 Ps write: 4 bf16 via 2 cvt_pk
            unsigned pk0, pk1;
            asm("v_cvt_pk_bf16_f32 %0, %1, %2" : "=v"(pk0) : "v"(p0), "v"(p1));
            asm("v_cvt_pk_bf16_f32 %0, %1, %2" : "=v"(pk1) : "v"(p2), "v"(p3));
            u32x2 pw = {pk0, pk1};
            *(u32x2*)((char*)&Ps[w][0] + li * 144 + kc * 32 + g * 8) = pw;
        }
        // this wave's Ps writes visible to its own reads
        asm volatile("s_waitcnt lgkmcnt(0)" ::: "memory");
        SB0;

        bf16x8 pf0 = *(const bf16x8*)((const char*)&Ps[w][0] + li * 144 + g * 16);
        bf16x8 pf1 = *(const bf16x8*)((const char*)&Ps[w][0] + li * 144 + 64 + g * 16);
        #pragma unroll
        for (int dt = 0; dt < 8; ++dt) {
            int dr = dt * 16 + li;
            int vsw = ((dr >> 3) & 7) << 4;
            bf16x8 vf0 = *(const bf16x8*)((const char*)Vt + dr * 128 + ((g * 16) ^ vsw));
            bf16x8 vf1 = *(const bf16x8*)((const char*)Vt + dr * 128 + ((64 + g * 16) ^ vsw));
            O[dt] = __builtin_amdgcn_mfma_f32_16x16x32_bf16(pf0, vf0, O[dt], 0, 0, 0);
            O[dt] = __builtin_amdgcn_mfma_f32_16x16x32_bf16(pf1, vf1, O[dt], 0, 0, 0);
        }
    }

    const int b = bh >> 3, h = bh & 7;
    #pragma unroll
    for (int dt = 0; dt < 8; ++dt) {
        #pragma unroll
        for (int i = 0; i < 4; ++i) {
            size_t r = (size_t)b * SS + q0 + g * 4 + i;
            Ob[r * EMB + h * DD + dt * 16 + li] = f2bf(O[dt][i]);
        }
    }
}

extern "C" void kernel_launch(void* const* d_in, const int* in_sizes, int n_in,
                              void* d_out, int out_size, void* d_ws, size_t ws_size,
                              hipStream_t stream)
{
    const float* q  = (const float*)d_in[0];
    const float* k  = (const float*)d_in[1];
    const float* v  = (const float*)d_in[2];
    const float* Wq = (const float*)d_in[3];
    const float* bq = (const float*)d_in[4];
    const float* Wk = (const float*)d_in[5];
    const float* bk = (const float*)d_in[6];
    const float* Wv = (const float*)d_in[7];
    const float* bv = (const float*)d_in[8];
    const float* Wo = (const float*)d_in[9];
    const float* bo = (const float*)d_in[10];

    const size_t NX = (size_t)BB * SS * EMB;   // 8,388,608
    const size_t NW = (size_t)EMB * EMB;       // 1,048,576

    unsigned short* Qb = (unsigned short*)d_ws;      // Qb|Kb|Vb contiguous
    unsigned short* Ob = Qb + 3 * NX;                // [B*S, EMB]
    unsigned short* WB = Ob + NX;                    // 4*NW bf16

    float* outx = (float*)d_out;             // [B,S,EMB]
    float* attn = outx + NX;                 // [B,H,S,S]
    unsigned short* XB = (unsigned short*)attn;  // staged bf16 q/k/v (overwritten later)

    f2bf3_kernel<<<dim3(1024, 1, 3), 256, 0, stream>>>(q, k, v, XB, (int)(NX / 4));
    f2bf4_kernel<<<dim3(128, 1, 4), 256, 0, stream>>>(Wq, Wk, Wv, Wo, WB, (int)(NW / 4));

    const float qscale = 1.4426950408889634f / sqrtf((float)DD); // log2(e)/sqrt(D)
    gemm_qkv<<<dim3(64, 8, 3), 256, 0, stream>>>(XB, WB, bq, bk, bv, Qb, qscale);

    attn_kernel<<<dim3(32, 32), 256, 0, stream>>>(Qb, Qb + NX, Qb + 2 * NX, attn, Ob);

    gemm_out<<<dim3(64, 8), 256, 0, stream>>>(Ob, WB + 3 * NW, bo, outx);
}